// Round 1
// baseline (3461.221 us; speedup 1.0000x reference)
//
#include <hip/hip_runtime.h>
#include <cstdint>

#define L_ 6
#define B_ 4
#define S_ 1024
#define E_ 1024
#define H_ 16
#define DH_ 64
#define F_ 4096
#define R_ (B_*S_)

typedef __attribute__((ext_vector_type(8))) short bf16x8;
typedef __attribute__((ext_vector_type(4))) float f32x4;
typedef __attribute__((ext_vector_type(4))) unsigned short u16x4;
typedef unsigned short u16;

__device__ __forceinline__ u16 f2bf(float f) {
  unsigned u = __float_as_uint(f);
  u += 0x7fffu + ((u >> 16) & 1u);
  return (u16)(u >> 16);
}

__device__ __forceinline__ void g2lds16(const void* g, void* l) {
  __builtin_amdgcn_global_load_lds(
      (const __attribute__((address_space(1))) void*)g,
      (__attribute__((address_space(3))) void*)l, 16, 0, 0);
}

// ---------------- weight transpose + fp32->bf16 ----------------
// in: [K,N] fp32 (per layer, blockIdx.z selects layer), out: [N,K] bf16
__global__ __launch_bounds__(256)
void transpose_w(const float* __restrict__ in, u16* __restrict__ out, int K, int N)
{
  __shared__ float t[32][33];
  const size_t mat = (size_t)K * N;
  const float* inp = in + (size_t)blockIdx.z * mat;
  u16* outp = out + (size_t)blockIdx.z * mat;
  const int tx = threadIdx.x, ty = threadIdx.y;
  const int n0 = blockIdx.x << 5, k0 = blockIdx.y << 5;
  #pragma unroll
  for (int i = ty; i < 32; i += 8)
    t[i][tx] = inp[(size_t)(k0 + i) * N + n0 + tx];
  __syncthreads();
  #pragma unroll
  for (int i = ty; i < 32; i += 8)
    outp[(size_t)(n0 + i) * K + k0 + tx] = f2bf(t[tx][i]);
}

// ---------------- elementwise helpers ----------------
__global__ void addf4_k(const f32x4* __restrict__ a, const f32x4* __restrict__ b,
                        f32x4* __restrict__ o, int n)
{
  for (int i = blockIdx.x * blockDim.x + threadIdx.x; i < n; i += gridDim.x * blockDim.x)
    o[i] = a[i] + b[i];
}

__global__ void copyf4_k(const f32x4* __restrict__ a, f32x4* __restrict__ o, int n)
{
  for (int i = blockIdx.x * blockDim.x + threadIdx.x; i < n; i += gridDim.x * blockDim.x)
    o[i] = a[i];
}

// ---------------- layernorm: fp32 in, bf16 (0) or fp32 (1) out ----------------
template<int OUTF32>
__global__ __launch_bounds__(256)
void ln_k(const float* __restrict__ in, const float* __restrict__ gam,
          const float* __restrict__ bet, void* __restrict__ out)
{
  const int row = blockIdx.x;
  const int t = threadIdx.x;
  const f32x4 x = ((const f32x4*)(in + (size_t)row * E_))[t];
  float s = x.x + x.y + x.z + x.w;
  float s2 = x.x*x.x + x.y*x.y + x.z*x.z + x.w*x.w;
  #pragma unroll
  for (int m = 1; m < 64; m <<= 1) { s += __shfl_xor(s, m); s2 += __shfl_xor(s2, m); }
  __shared__ float red[8];
  const int w = t >> 6, lane = t & 63;
  if (lane == 0) { red[w] = s; red[4 + w] = s2; }
  __syncthreads();
  s  = red[0] + red[1] + red[2] + red[3];
  s2 = red[4] + red[5] + red[6] + red[7];
  const float mean = s * (1.0f / E_);
  const float var  = s2 * (1.0f / E_) - mean * mean;
  const float rstd = rsqrtf(var + 1e-5f);
  const f32x4 g = ((const f32x4*)gam)[t];
  const f32x4 b = ((const f32x4*)bet)[t];
  f32x4 y;
  y.x = (x.x - mean) * rstd * g.x + b.x;
  y.y = (x.y - mean) * rstd * g.y + b.y;
  y.z = (x.z - mean) * rstd * g.z + b.z;
  y.w = (x.w - mean) * rstd * g.w + b.w;
  if (OUTF32) {
    ((f32x4*)out)[(size_t)row * 256 + t] = y;
  } else {
    u16x4 p;
    p.x = f2bf(y.x); p.y = f2bf(y.y); p.z = f2bf(y.z); p.w = f2bf(y.w);
    ((u16x4*)out)[(size_t)row * 256 + t] = p;
  }
}

// ---------------- GEMM: C[M,N] = A[M,K] @ Bt[N,K]^T + bias ----------------
enum { MODE_BF16 = 0, MODE_GELU = 1, MODE_RES = 2, MODE_VT = 3 };

template<int MODE>
__global__ __launch_bounds__(256)
void gemm_k(const u16* __restrict__ A, const u16* __restrict__ Bt,
            const float* __restrict__ bias, u16* __restrict__ outb,
            float* __restrict__ outf, int N, int K)
{
  __shared__ __align__(16) u16 As[128 * 32];
  __shared__ __align__(16) u16 Bs[128 * 32];
  const int m0 = blockIdx.y << 7, n0 = blockIdx.x << 7;
  const int tid = threadIdx.x, w = tid >> 6, lane = tid & 63;
  const int l15 = lane & 15, l4 = lane >> 4;
  const int wm = (w & 1) << 6, wn = (w >> 1) << 6;
  f32x4 acc[4][4] = {};
  const int arow0 = (w << 5) + (lane >> 2);           // c=0 row, +16 for c=1
  const size_t aoff = (size_t)(lane & 3) << 3;        // 8-elem (16B) sub-offset
  for (int kk = 0; kk < K; kk += 32) {
    const u16* ga0 = A  + (size_t)(m0 + arow0) * K + kk + aoff;
    const u16* gb0 = Bt + (size_t)(n0 + arow0) * K + kk + aoff;
    g2lds16(ga0,                 &As[((w << 5) + 0 ) * 32]);
    g2lds16(ga0 + (size_t)16 * K, &As[((w << 5) + 16) * 32]);
    g2lds16(gb0,                 &Bs[((w << 5) + 0 ) * 32]);
    g2lds16(gb0 + (size_t)16 * K, &Bs[((w << 5) + 16) * 32]);
    __syncthreads();
    bf16x8 af[4], bfr[4];
    #pragma unroll
    for (int t = 0; t < 4; ++t) {
      af[t]  = *(const bf16x8*)&As[(wm + (t << 4) + l15) * 32 + (l4 << 3)];
      bfr[t] = *(const bf16x8*)&Bs[(wn + (t << 4) + l15) * 32 + (l4 << 3)];
    }
    #pragma unroll
    for (int mt = 0; mt < 4; ++mt)
      #pragma unroll
      for (int nt = 0; nt < 4; ++nt)
        acc[mt][nt] = __builtin_amdgcn_mfma_f32_16x16x32_bf16(af[mt], bfr[nt], acc[mt][nt], 0, 0, 0);
    __syncthreads();
  }
  float bv[4];
  #pragma unroll
  for (int nt = 0; nt < 4; ++nt) bv[nt] = bias[n0 + wn + (nt << 4) + l15];
  #pragma unroll
  for (int mt = 0; mt < 4; ++mt) {
    #pragma unroll
    for (int nt = 0; nt < 4; ++nt) {
      #pragma unroll
      for (int r = 0; r < 4; ++r) {
        const int row = m0 + wm + (mt << 4) + (l4 << 2) + r;
        const int col = n0 + wn + (nt << 4) + l15;
        float v = acc[mt][nt][r] + bv[nt];
        if (MODE == MODE_BF16) {
          outb[(size_t)row * N + col] = f2bf(v);
        } else if (MODE == MODE_GELU) {
          v = 0.5f * v * (1.0f + erff(v * 0.70710678118f));
          outb[(size_t)row * N + col] = f2bf(v);
        } else if (MODE == MODE_RES) {
          outf[(size_t)row * N + col] += v;
        } else { // MODE_VT: out[(b*H+h)*DH+dh][s]
          const int bb = row >> 10, ss = row & 1023, hh = col >> 6, dh = col & 63;
          outb[((size_t)((bb << 4) + hh) * DH_ + dh) * S_ + ss] = f2bf(v);
        }
      }
    }
  }
}

// ---------------- flash attention ----------------
// q,k: [B,S,H*DH] bf16; vT: [B*H, DH, S] bf16; bias: [B,S,S] fp32; out: [B,S,H*DH] bf16
__global__ __launch_bounds__(256)
void attn_k(const u16* __restrict__ q, const u16* __restrict__ k,
            const u16* __restrict__ vT, const float* __restrict__ bias,
            u16* __restrict__ out)
{
  __shared__ __align__(16) u16 P[4][16 * 64];
  const int tid = threadIdx.x;
  const int w = tid >> 6, lane = tid & 63;
  const int l15 = lane & 15, l4 = lane >> 4;
  const int bh = blockIdx.y, b = bh >> 4, hh = bh & 15;
  const int q0 = (blockIdx.x << 6) + (w << 4);
  const size_t qrowbase = (size_t)(b * S_ + q0 + l15) * E_ + hh * DH_ + (l4 << 3);
  const bf16x8 aq0 = *(const bf16x8*)(q + qrowbase);
  const bf16x8 aq1 = *(const bf16x8*)(q + qrowbase + 32);
  f32x4 o[4] = {};
  float mrow[4] = {-__builtin_inff(), -__builtin_inff(), -__builtin_inff(), -__builtin_inff()};
  float lrow[4] = {0.f, 0.f, 0.f, 0.f};
  u16* Pw = &P[w][0];
  for (int kt = 0; kt < S_ / 64; ++kt) {
    const int kb = kt << 6;
    f32x4 sc[4];
    #pragma unroll
    for (int nt = 0; nt < 4; ++nt) {
      const size_t kbase = (size_t)(b * S_ + kb + (nt << 4) + l15) * E_ + hh * DH_ + (l4 << 3);
      const bf16x8 kb0 = *(const bf16x8*)(k + kbase);
      const bf16x8 kb1 = *(const bf16x8*)(k + kbase + 32);
      f32x4 z = {};
      z = __builtin_amdgcn_mfma_f32_16x16x32_bf16(aq0, kb0, z, 0, 0, 0);
      z = __builtin_amdgcn_mfma_f32_16x16x32_bf16(aq1, kb1, z, 0, 0, 0);
      sc[nt] = z;
    }
    float al[4];
    #pragma unroll
    for (int r = 0; r < 4; ++r) {
      const float* bp = bias + (size_t)(b * S_ + q0 + (l4 << 2) + r) * S_ + kb + l15;
      float t = -__builtin_inff();
      #pragma unroll
      for (int nt = 0; nt < 4; ++nt) {
        sc[nt][r] = sc[nt][r] * 0.125f + bp[nt << 4];
        t = fmaxf(t, sc[nt][r]);
      }
      #pragma unroll
      for (int mk = 1; mk <= 8; mk <<= 1) t = fmaxf(t, __shfl_xor(t, mk));
      const float mnew = fmaxf(mrow[r], t);
      al[r] = __expf(mrow[r] - mnew);
      mrow[r] = mnew;
      float rs = 0.f;
      #pragma unroll
      for (int nt = 0; nt < 4; ++nt) {
        const float p = __expf(sc[nt][r] - mnew);
        sc[nt][r] = p;
        rs += p;
      }
      #pragma unroll
      for (int mk = 1; mk <= 8; mk <<= 1) rs += __shfl_xor(rs, mk);
      lrow[r] = lrow[r] * al[r] + rs;
    }
    #pragma unroll
    for (int ct = 0; ct < 4; ++ct) {
      o[ct][0] *= al[0]; o[ct][1] *= al[1]; o[ct][2] *= al[2]; o[ct][3] *= al[3];
    }
    #pragma unroll
    for (int nt = 0; nt < 4; ++nt)
      #pragma unroll
      for (int r = 0; r < 4; ++r)
        Pw[((l4 << 2) + r) * 64 + (nt << 4) + l15] = f2bf(sc[nt][r]);
    asm volatile("s_waitcnt lgkmcnt(0)" ::: "memory");
    const bf16x8 pa0 = *(const bf16x8*)&Pw[l15 * 64 + (l4 << 3)];
    const bf16x8 pa1 = *(const bf16x8*)&Pw[l15 * 64 + 32 + (l4 << 3)];
    #pragma unroll
    for (int ct = 0; ct < 4; ++ct) {
      const size_t vb = (size_t)(bh * DH_ + (ct << 4) + l15) * S_ + kb + (l4 << 3);
      const bf16x8 v0 = *(const bf16x8*)(vT + vb);
      const bf16x8 v1 = *(const bf16x8*)(vT + vb + 32);
      o[ct] = __builtin_amdgcn_mfma_f32_16x16x32_bf16(pa0, v0, o[ct], 0, 0, 0);
      o[ct] = __builtin_amdgcn_mfma_f32_16x16x32_bf16(pa1, v1, o[ct], 0, 0, 0);
    }
  }
  #pragma unroll
  for (int r = 0; r < 4; ++r) {
    const float linv = 1.0f / lrow[r];
    const size_t rowoff = (size_t)(b * S_ + q0 + (l4 << 2) + r) * E_ + hh * DH_;
    #pragma unroll
    for (int ct = 0; ct < 4; ++ct)
      out[rowoff + (ct << 4) + l15] = f2bf(o[ct][r] * linv);
  }
}

// ---------------- host ----------------
extern "C" void kernel_launch(void* const* d_in, const int* in_sizes, int n_in,
                              void* d_out, int out_size, void* d_ws, size_t ws_size,
                              hipStream_t stream)
{
  (void)in_sizes; (void)n_in; (void)out_size; (void)ws_size;
  const float* src     = (const float*)d_in[0];
  const float* spatial = (const float*)d_in[1];
  const float* direc   = (const float*)d_in[2];
  const float* Wq = (const float*)d_in[3];
  const float* bq = (const float*)d_in[4];
  const float* Wk = (const float*)d_in[5];
  const float* bk = (const float*)d_in[6];
  const float* Wv = (const float*)d_in[7];
  const float* bv = (const float*)d_in[8];
  const float* Wo = (const float*)d_in[9];
  const float* bo = (const float*)d_in[10];
  const float* g1  = (const float*)d_in[11];
  const float* be1 = (const float*)d_in[12];
  const float* g2  = (const float*)d_in[13];
  const float* be2 = (const float*)d_in[14];
  const float* W1  = (const float*)d_in[15];
  const float* bf1 = (const float*)d_in[16];
  const float* W2  = (const float*)d_in[17];
  const float* bf2 = (const float*)d_in[18];
  const float* gf  = (const float*)d_in[19];
  const float* bef = (const float*)d_in[20];

  const size_t EE = (size_t)E_ * E_;
  const size_t EF = (size_t)E_ * F_;
  u16* wqt = (u16*)d_ws;
  u16* wkt = wqt + L_ * EE;
  u16* wvt = wkt + L_ * EE;
  u16* wot = wvt + L_ * EE;
  u16* w1t = wot + L_ * EE;
  u16* w2t = w1t + L_ * EF;
  float* x = (float*)(w2t + L_ * EF);
  u16* h   = (u16*)(x + (size_t)R_ * E_);
  u16* qb  = h  + (size_t)R_ * E_;
  u16* kb  = qb + (size_t)R_ * E_;
  u16* vtb = kb + (size_t)R_ * E_;
  u16* ab  = vtb + (size_t)R_ * E_;
  u16* mid = qb;  // reuse q..attn region (32 MiB) for FFN intermediate
  float* bsum = (float*)(ab + (size_t)R_ * E_);

  const dim3 tb(32, 8);
  transpose_w<<<dim3(E_/32, E_/32, L_), tb, 0, stream>>>(Wq, wqt, E_, E_);
  transpose_w<<<dim3(E_/32, E_/32, L_), tb, 0, stream>>>(Wk, wkt, E_, E_);
  transpose_w<<<dim3(E_/32, E_/32, L_), tb, 0, stream>>>(Wv, wvt, E_, E_);
  transpose_w<<<dim3(E_/32, E_/32, L_), tb, 0, stream>>>(Wo, wot, E_, E_);
  transpose_w<<<dim3(F_/32, E_/32, L_), tb, 0, stream>>>(W1, w1t, E_, F_);
  transpose_w<<<dim3(E_/32, F_/32, L_), tb, 0, stream>>>(W2, w2t, F_, E_);

  const int n4 = (B_ * S_ * S_) / 4;
  addf4_k<<<1024, 256, 0, stream>>>((const f32x4*)spatial, (const f32x4*)direc, (f32x4*)bsum, n4);
  copyf4_k<<<1024, 256, 0, stream>>>((const f32x4*)src, (f32x4*)x, (R_ * E_) / 4);

  const dim3 gq(E_/128, R_/128);
  for (int l = 0; l < L_; ++l) {
    const size_t we = l * EE, wf = l * EF;
    ln_k<0><<<R_, 256, 0, stream>>>(x, g1 + l*E_, be1 + l*E_, (void*)h);
    gemm_k<MODE_BF16><<<gq, 256, 0, stream>>>(h, wqt + we, bq + l*E_, qb,  nullptr, E_, E_);
    gemm_k<MODE_BF16><<<gq, 256, 0, stream>>>(h, wkt + we, bk + l*E_, kb,  nullptr, E_, E_);
    gemm_k<MODE_VT>  <<<gq, 256, 0, stream>>>(h, wvt + we, bv + l*E_, vtb, nullptr, E_, E_);
    attn_k<<<dim3(S_/64, B_*H_), 256, 0, stream>>>(qb, kb, vtb, bsum, ab);
    gemm_k<MODE_RES> <<<gq, 256, 0, stream>>>(ab, wot + we, bo + l*E_, nullptr, x, E_, E_);
    ln_k<0><<<R_, 256, 0, stream>>>(x, g2 + l*E_, be2 + l*E_, (void*)h);
    gemm_k<MODE_GELU><<<dim3(F_/128, R_/128), 256, 0, stream>>>(h, w1t + wf, bf1 + l*F_, mid, nullptr, F_, E_);
    gemm_k<MODE_RES> <<<dim3(E_/128, R_/128), 256, 0, stream>>>(mid, w2t + wf, bf2 + l*E_, nullptr, x, E_, F_);
  }
  ln_k<1><<<R_, 256, 0, stream>>>(x, gf, bef, d_out);
}

// Round 2
// 2665.277 us; speedup vs baseline: 1.2986x; 1.2986x over previous
//
#include <hip/hip_runtime.h>
#include <cstdint>

#define L_ 6
#define B_ 4
#define S_ 1024
#define E_ 1024
#define H_ 16
#define DH_ 64
#define F_ 4096
#define R_ (B_*S_)

typedef __attribute__((ext_vector_type(8))) short bf16x8;
typedef __attribute__((ext_vector_type(4))) float f32x4;
typedef __attribute__((ext_vector_type(4))) unsigned short u16x4;
typedef unsigned short u16;

__device__ __forceinline__ u16 f2bf(float f) {
  unsigned u = __float_as_uint(f);
  u += 0x7fffu + ((u >> 16) & 1u);
  return (u16)(u >> 16);
}

__device__ __forceinline__ void g2lds16(const void* g, void* l) {
  __builtin_amdgcn_global_load_lds(
      (const __attribute__((address_space(1))) void*)g,
      (__attribute__((address_space(3))) void*)l, 16, 0, 0);
}

// ---------------- weight transpose + fp32->bf16 ----------------
// in: [K,N] fp32 (blockIdx.z = layer), out: out + z*ostride + obase, [N,K] bf16
__global__ __launch_bounds__(256)
void transpose_w(const float* __restrict__ in, u16* __restrict__ out, int K, int N,
                 size_t ostride, size_t obase)
{
  __shared__ float t[32][33];
  const float* inp = in + (size_t)blockIdx.z * K * N;
  u16* outp = out + (size_t)blockIdx.z * ostride + obase;
  const int tx = threadIdx.x, ty = threadIdx.y;
  const int n0 = blockIdx.x << 5, k0 = blockIdx.y << 5;
  #pragma unroll
  for (int i = ty; i < 32; i += 8)
    t[i][tx] = inp[(size_t)(k0 + i) * N + n0 + tx];
  __syncthreads();
  #pragma unroll
  for (int i = ty; i < 32; i += 8)
    outp[(size_t)(n0 + i) * K + k0 + tx] = f2bf(t[tx][i]);
}

// ---------------- elementwise helpers ----------------
__global__ void addf4_k(const f32x4* __restrict__ a, const f32x4* __restrict__ b,
                        f32x4* __restrict__ o, int n)
{
  for (int i = blockIdx.x * blockDim.x + threadIdx.x; i < n; i += gridDim.x * blockDim.x)
    o[i] = a[i] + b[i];
}

__global__ void copyf4_k(const f32x4* __restrict__ a, f32x4* __restrict__ o, int n)
{
  for (int i = blockIdx.x * blockDim.x + threadIdx.x; i < n; i += gridDim.x * blockDim.x)
    o[i] = a[i];
}

// pack bq/bk/bv -> [L][3E]
__global__ void packb_k(const float* __restrict__ bq, const float* __restrict__ bk,
                        const float* __restrict__ bv, float* __restrict__ o)
{
  const int i = blockIdx.x * 256 + threadIdx.x;
  const int l = i / (3 * E_), j = i % (3 * E_);
  float v;
  if (j < E_) v = bq[l * E_ + j];
  else if (j < 2 * E_) v = bk[l * E_ + j - E_];
  else v = bv[l * E_ + j - 2 * E_];
  o[i] = v;
}

// ---------------- layernorm: fp32 in, bf16 (0) or fp32 (1) out ----------------
template<int OUTF32>
__global__ __launch_bounds__(256)
void ln_k(const float* __restrict__ in, const float* __restrict__ gam,
          const float* __restrict__ bet, void* __restrict__ out)
{
  const int row = blockIdx.x;
  const int t = threadIdx.x;
  const f32x4 x = ((const f32x4*)(in + (size_t)row * E_))[t];
  float s = x.x + x.y + x.z + x.w;
  float s2 = x.x*x.x + x.y*x.y + x.z*x.z + x.w*x.w;
  #pragma unroll
  for (int m = 1; m < 64; m <<= 1) { s += __shfl_xor(s, m); s2 += __shfl_xor(s2, m); }
  __shared__ float red[8];
  const int w = t >> 6, lane = t & 63;
  if (lane == 0) { red[w] = s; red[4 + w] = s2; }
  __syncthreads();
  s  = red[0] + red[1] + red[2] + red[3];
  s2 = red[4] + red[5] + red[6] + red[7];
  const float mean = s * (1.0f / E_);
  const float var  = s2 * (1.0f / E_) - mean * mean;
  const float rstd = rsqrtf(var + 1e-5f);
  const f32x4 g = ((const f32x4*)gam)[t];
  const f32x4 b = ((const f32x4*)bet)[t];
  f32x4 y;
  y.x = (x.x - mean) * rstd * g.x + b.x;
  y.y = (x.y - mean) * rstd * g.y + b.y;
  y.z = (x.z - mean) * rstd * g.z + b.z;
  y.w = (x.w - mean) * rstd * g.w + b.w;
  if (OUTF32) {
    ((f32x4*)out)[(size_t)row * 256 + t] = y;
  } else {
    u16x4 p;
    p.x = f2bf(y.x); p.y = f2bf(y.y); p.z = f2bf(y.z); p.w = f2bf(y.w);
    ((u16x4*)out)[(size_t)row * 256 + t] = p;
  }
}

// ---------------- GEMM: C[M,N] = A[M,K] @ Bt[N,K]^T + bias ----------------
enum { MODE_BF16 = 0, MODE_GELU = 1, MODE_RES = 2, MODE_QKV = 4 };

template<int MODE>
__global__ __launch_bounds__(256)
void gemm_k(const u16* __restrict__ A, const u16* __restrict__ Bt,
            const float* __restrict__ bias, u16* __restrict__ outb,
            float* __restrict__ outf, int N, int K)
{
  __shared__ __align__(16) u16 As[128 * 32];
  __shared__ __align__(16) u16 Bs[128 * 32];
  const int m0 = blockIdx.y << 7, n0 = blockIdx.x << 7;
  const int tid = threadIdx.x, w = tid >> 6, lane = tid & 63;
  const int l15 = lane & 15, l4 = lane >> 4;
  const int wm = (w & 1) << 6, wn = (w >> 1) << 6;
  f32x4 acc[4][4] = {};
  const int arow0 = (w << 5) + (lane >> 2);
  const size_t aoff = (size_t)(lane & 3) << 3;
  for (int kk = 0; kk < K; kk += 32) {
    const u16* ga0 = A  + (size_t)(m0 + arow0) * K + kk + aoff;
    const u16* gb0 = Bt + (size_t)(n0 + arow0) * K + kk + aoff;
    g2lds16(ga0,                  &As[((w << 5) + 0 ) * 32]);
    g2lds16(ga0 + (size_t)16 * K, &As[((w << 5) + 16) * 32]);
    g2lds16(gb0,                  &Bs[((w << 5) + 0 ) * 32]);
    g2lds16(gb0 + (size_t)16 * K, &Bs[((w << 5) + 16) * 32]);
    __syncthreads();
    bf16x8 af[4], bfr[4];
    #pragma unroll
    for (int t = 0; t < 4; ++t) {
      af[t]  = *(const bf16x8*)&As[(wm + (t << 4) + l15) * 32 + (l4 << 3)];
      bfr[t] = *(const bf16x8*)&Bs[(wn + (t << 4) + l15) * 32 + (l4 << 3)];
    }
    #pragma unroll
    for (int mt = 0; mt < 4; ++mt)
      #pragma unroll
      for (int nt = 0; nt < 4; ++nt)
        acc[mt][nt] = __builtin_amdgcn_mfma_f32_16x16x32_bf16(af[mt], bfr[nt], acc[mt][nt], 0, 0, 0);
    __syncthreads();
  }
  float bv[4];
  #pragma unroll
  for (int nt = 0; nt < 4; ++nt) bv[nt] = bias[n0 + wn + (nt << 4) + l15];
  #pragma unroll
  for (int mt = 0; mt < 4; ++mt) {
    #pragma unroll
    for (int nt = 0; nt < 4; ++nt) {
      #pragma unroll
      for (int r = 0; r < 4; ++r) {
        const int row = m0 + wm + (mt << 4) + (l4 << 2) + r;
        const int col = n0 + wn + (nt << 4) + l15;
        float v = acc[mt][nt][r] + bv[nt];
        if (MODE == MODE_BF16) {
          outb[(size_t)row * N + col] = f2bf(v);
        } else if (MODE == MODE_GELU) {
          v = 0.5f * v * (1.0f + erff(v * 0.70710678118f));
          outb[(size_t)row * N + col] = f2bf(v);
        } else if (MODE == MODE_RES) {
          outf[(size_t)row * N + col] += v;
        } else { // MODE_QKV: col -> part (q|k|vT); buffers contiguous at outb
          const int part = col >> 10, c = col & 1023;
          if (part == 0) {
            outb[(size_t)row * E_ + c] = f2bf(v);
          } else if (part == 1) {
            outb[(size_t)R_ * E_ + (size_t)row * E_ + c] = f2bf(v);
          } else {
            const int bb = row >> 10, ss = row & 1023, hh = c >> 6, dh = c & 63;
            outb[(size_t)2 * R_ * E_ + ((size_t)((bb << 4) + hh) * DH_ + dh) * S_ + ss] = f2bf(v);
          }
        }
      }
    }
  }
}

// ---------------- flash attention, LDS-staged ----------------
// q,k: [B,S,H*DH] bf16; vT: [B*H, DH, S] bf16; bias: [B,S,S] fp32; out: [B,S,H*DH] bf16
__global__ __launch_bounds__(256)
void attn_k(const u16* __restrict__ q, const u16* __restrict__ kg,
            const u16* __restrict__ vT, const float* __restrict__ bias,
            u16* __restrict__ out)
{
  __shared__ __align__(16) u16 Ks[64 * 64];   // [s][dh], xor-swizzled 16B chunks
  __shared__ __align__(16) u16 Vs[64 * 64];   // [dh][s], xor-swizzled 16B chunks
  __shared__ __align__(16) float Bsh[64 * 64]; // [qrow][s]
  __shared__ __align__(16) u16 P[4][16 * 72];  // per-wave, padded stride 72 (144B, 16B-mult)
  const int tid = threadIdx.x, w = tid >> 6, lane = tid & 63;
  const int l15 = lane & 15, l4 = lane >> 4;
  const int bh = blockIdx.y, b = bh >> 4, hh = bh & 15;
  const int q0 = blockIdx.x << 6;
  const int qw = q0 + (w << 4);
  const size_t qrowbase = (size_t)(b * S_ + qw + l15) * E_ + hh * DH_ + (l4 << 3);
  const bf16x8 aq0 = *(const bf16x8*)(q + qrowbase);
  const bf16x8 aq1 = *(const bf16x8*)(q + qrowbase + 32);
  f32x4 o[4] = {};
  float mrow[4] = {-__builtin_inff(), -__builtin_inff(), -__builtin_inff(), -__builtin_inff()};
  float lrow[4] = {0.f, 0.f, 0.f, 0.f};
  u16* Pw = &P[w][0];
  // staging roles
  const int srow = lane >> 3;                       // 0..7
  const int scg8 = ((lane & 7) ^ srow) << 3;        // xor-swizzled 8-elem chunk
  const int brow = lane >> 4;                       // bias: 0..3
  const int bcol = (lane & 15) << 2;                // bias: 4-float chunk
  // fragment chunk positions (undo swizzle at read)
  const int kpos0 = (l4 ^ (l15 & 7)) << 3;
  const int kpos1 = ((l4 + 4) ^ (l15 & 7)) << 3;

  for (int kt = 0; kt < S_ / 64; ++kt) {
    const int kb = kt << 6;
    {
      const u16* gk = kg + (size_t)(b * S_ + kb + (w << 4) + srow) * E_ + hh * DH_ + scg8;
      g2lds16(gk,                  &Ks[(w << 10) + (lane << 3)]);
      g2lds16(gk + (size_t)8 * E_, &Ks[(w << 10) + 512 + (lane << 3)]);
      const u16* gv = vT + (size_t)(bh * DH_ + (w << 4) + srow) * S_ + kb + scg8;
      g2lds16(gv,                  &Vs[(w << 10) + (lane << 3)]);
      g2lds16(gv + (size_t)8 * S_, &Vs[(w << 10) + 512 + (lane << 3)]);
      const float* gb = bias + (size_t)(b * S_ + q0 + (w << 4) + brow) * S_ + kb + bcol;
      g2lds16(gb,                   &Bsh[(w << 10) + (lane << 2)]);
      g2lds16(gb + (size_t)4 * S_,  &Bsh[(w << 10) + 256 + (lane << 2)]);
      g2lds16(gb + (size_t)8 * S_,  &Bsh[(w << 10) + 512 + (lane << 2)]);
      g2lds16(gb + (size_t)12 * S_, &Bsh[(w << 10) + 768 + (lane << 2)]);
    }
    __syncthreads();
    // QK^T
    f32x4 sc[4];
    #pragma unroll
    for (int nt = 0; nt < 4; ++nt) {
      const int krow = ((nt << 4) + l15) * 64;
      const bf16x8 kf0 = *(const bf16x8*)&Ks[krow + kpos0];
      const bf16x8 kf1 = *(const bf16x8*)&Ks[krow + kpos1];
      f32x4 z = {};
      z = __builtin_amdgcn_mfma_f32_16x16x32_bf16(aq0, kf0, z, 0, 0, 0);
      z = __builtin_amdgcn_mfma_f32_16x16x32_bf16(aq1, kf1, z, 0, 0, 0);
      sc[nt] = z;
    }
    // online softmax
    float al[4];
    #pragma unroll
    for (int r = 0; r < 4; ++r) {
      const float* bp = &Bsh[((w << 4) + (l4 << 2) + r) * 64 + l15];
      float t = -__builtin_inff();
      #pragma unroll
      for (int nt = 0; nt < 4; ++nt) {
        sc[nt][r] = sc[nt][r] * 0.125f + bp[nt << 4];
        t = fmaxf(t, sc[nt][r]);
      }
      #pragma unroll
      for (int mk = 1; mk <= 8; mk <<= 1) t = fmaxf(t, __shfl_xor(t, mk));
      const float mnew = fmaxf(mrow[r], t);
      al[r] = __expf(mrow[r] - mnew);
      mrow[r] = mnew;
      float rs = 0.f;
      #pragma unroll
      for (int nt = 0; nt < 4; ++nt) {
        const float p = __expf(sc[nt][r] - mnew);
        sc[nt][r] = p;
        rs += p;
      }
      #pragma unroll
      for (int mk = 1; mk <= 8; mk <<= 1) rs += __shfl_xor(rs, mk);
      lrow[r] = lrow[r] * al[r] + rs;
    }
    #pragma unroll
    for (int ct = 0; ct < 4; ++ct) {
      o[ct][0] *= al[0]; o[ct][1] *= al[1]; o[ct][2] *= al[2]; o[ct][3] *= al[3];
    }
    // P -> LDS (C-layout -> A-layout round trip)
    #pragma unroll
    for (int nt = 0; nt < 4; ++nt)
      #pragma unroll
      for (int r = 0; r < 4; ++r)
        Pw[((l4 << 2) + r) * 72 + (nt << 4) + l15] = f2bf(sc[nt][r]);
    asm volatile("s_waitcnt lgkmcnt(0)" ::: "memory");
    const bf16x8 pa0 = *(const bf16x8*)&Pw[l15 * 72 + (l4 << 3)];
    const bf16x8 pa1 = *(const bf16x8*)&Pw[l15 * 72 + 32 + (l4 << 3)];
    // P @ V
    #pragma unroll
    for (int ct = 0; ct < 4; ++ct) {
      const int vrow = ((ct << 4) + l15) * 64;
      const bf16x8 v0 = *(const bf16x8*)&Vs[vrow + kpos0];
      const bf16x8 v1 = *(const bf16x8*)&Vs[vrow + kpos1];
      o[ct] = __builtin_amdgcn_mfma_f32_16x16x32_bf16(pa0, v0, o[ct], 0, 0, 0);
      o[ct] = __builtin_amdgcn_mfma_f32_16x16x32_bf16(pa1, v1, o[ct], 0, 0, 0);
    }
    __syncthreads();
  }
  #pragma unroll
  for (int r = 0; r < 4; ++r) {
    const float linv = 1.0f / lrow[r];
    const size_t rowoff = (size_t)(b * S_ + qw + (l4 << 2) + r) * E_ + hh * DH_;
    #pragma unroll
    for (int ct = 0; ct < 4; ++ct)
      out[rowoff + (ct << 4) + l15] = f2bf(o[ct][r] * linv);
  }
}

// ---------------- host ----------------
extern "C" void kernel_launch(void* const* d_in, const int* in_sizes, int n_in,
                              void* d_out, int out_size, void* d_ws, size_t ws_size,
                              hipStream_t stream)
{
  (void)in_sizes; (void)n_in; (void)out_size; (void)ws_size;
  const float* src     = (const float*)d_in[0];
  const float* spatial = (const float*)d_in[1];
  const float* direc   = (const float*)d_in[2];
  const float* Wq = (const float*)d_in[3];
  const float* bq = (const float*)d_in[4];
  const float* Wk = (const float*)d_in[5];
  const float* bk = (const float*)d_in[6];
  const float* Wv = (const float*)d_in[7];
  const float* bv = (const float*)d_in[8];
  const float* Wo = (const float*)d_in[9];
  const float* bo = (const float*)d_in[10];
  const float* g1  = (const float*)d_in[11];
  const float* be1 = (const float*)d_in[12];
  const float* g2  = (const float*)d_in[13];
  const float* be2 = (const float*)d_in[14];
  const float* W1  = (const float*)d_in[15];
  const float* bf1 = (const float*)d_in[16];
  const float* W2  = (const float*)d_in[17];
  const float* bf2 = (const float*)d_in[18];
  const float* gf  = (const float*)d_in[19];
  const float* bef = (const float*)d_in[20];

  const size_t EE = (size_t)E_ * E_;
  const size_t EF = (size_t)E_ * F_;
  u16* wqkvt = (u16*)d_ws;                  // [L][3E][E]
  u16* wot = wqkvt + (size_t)L_ * 3 * EE;   // [L][E][E]
  u16* w1t = wot + (size_t)L_ * EE;         // [L][F][E]
  u16* w2t = w1t + (size_t)L_ * EF;         // [L][E][F]
  float* x = (float*)(w2t + (size_t)L_ * EF);
  u16* h   = (u16*)(x + (size_t)R_ * E_);
  u16* qb  = h  + (size_t)R_ * E_;          // q | k | vT contiguous (3 * R*E)
  u16* kb  = qb + (size_t)R_ * E_;
  u16* vtb = kb + (size_t)R_ * E_;
  u16* ab  = vtb + (size_t)R_ * E_;
  u16* mid = qb;                            // FFN mid reuses qkv+attn region (32 MiB)
  float* bsum = (float*)(ab + (size_t)R_ * E_);
  float* bqkv = bsum + (size_t)B_ * S_ * S_; // [L][3E]

  const dim3 tb(32, 8);
  transpose_w<<<dim3(E_/32, E_/32, L_), tb, 0, stream>>>(Wq, wqkvt, E_, E_, 3*EE, 0);
  transpose_w<<<dim3(E_/32, E_/32, L_), tb, 0, stream>>>(Wk, wqkvt, E_, E_, 3*EE, EE);
  transpose_w<<<dim3(E_/32, E_/32, L_), tb, 0, stream>>>(Wv, wqkvt, E_, E_, 3*EE, 2*EE);
  transpose_w<<<dim3(E_/32, E_/32, L_), tb, 0, stream>>>(Wo, wot, E_, E_, EE, 0);
  transpose_w<<<dim3(F_/32, E_/32, L_), tb, 0, stream>>>(W1, w1t, E_, F_, EF, 0);
  transpose_w<<<dim3(E_/32, F_/32, L_), tb, 0, stream>>>(W2, w2t, F_, E_, EF, 0);
  packb_k<<<(L_ * 3 * E_) / 256, 256, 0, stream>>>(bq, bk, bv, bqkv);

  const int n4 = (B_ * S_ * S_) / 4;
  addf4_k<<<1024, 256, 0, stream>>>((const f32x4*)spatial, (const f32x4*)direc, (f32x4*)bsum, n4);
  copyf4_k<<<1024, 256, 0, stream>>>((const f32x4*)src, (f32x4*)x, (R_ * E_) / 4);

  for (int l = 0; l < L_; ++l) {
    const size_t we = l * EE, wf = l * EF;
    ln_k<0><<<R_, 256, 0, stream>>>(x, g1 + l*E_, be1 + l*E_, (void*)h);
    gemm_k<MODE_QKV><<<dim3(3*E_/128, R_/128), 256, 0, stream>>>(h, wqkvt + l*3*EE, bqkv + (size_t)l*3*E_, qb, nullptr, 3*E_, E_);
    attn_k<<<dim3(S_/64, B_*H_), 256, 0, stream>>>(qb, kb, vtb, bsum, ab);
    gemm_k<MODE_RES> <<<dim3(E_/128, R_/128), 256, 0, stream>>>(ab, wot + we, bo + l*E_, nullptr, x, E_, E_);
    ln_k<0><<<R_, 256, 0, stream>>>(x, g2 + l*E_, be2 + l*E_, (void*)h);
    gemm_k<MODE_GELU><<<dim3(F_/128, R_/128), 256, 0, stream>>>(h, w1t + wf, bf1 + l*F_, mid, nullptr, F_, E_);
    gemm_k<MODE_RES> <<<dim3(E_/128, R_/128), 256, 0, stream>>>(mid, w2t + wf, bf2 + l*E_, nullptr, x, E_, F_);
  }
  ln_k<1><<<R_, 256, 0, stream>>>(x, gf, bef, d_out);
}

// Round 3
// 2384.686 us; speedup vs baseline: 1.4514x; 1.1177x over previous
//
#include <hip/hip_runtime.h>
#include <cstdint>

#define L_ 6
#define B_ 4
#define S_ 1024
#define E_ 1024
#define H_ 16
#define DH_ 64
#define F_ 4096
#define R_ (B_*S_)

typedef __attribute__((ext_vector_type(8))) short bf16x8;
typedef __attribute__((ext_vector_type(4))) float f32x4;
typedef __attribute__((ext_vector_type(4))) unsigned short u16x4;
typedef unsigned short u16;

__device__ __forceinline__ u16 f2bf(float f) {
  unsigned u = __float_as_uint(f);
  u += 0x7fffu + ((u >> 16) & 1u);
  return (u16)(u >> 16);
}

__device__ __forceinline__ void g2lds16(const void* g, void* l) {
  __builtin_amdgcn_global_load_lds(
      (const __attribute__((address_space(1))) void*)g,
      (__attribute__((address_space(3))) void*)l, 16, 0, 0);
}

// ---------------- weight transpose + fp32->bf16 ----------------
__global__ __launch_bounds__(256)
void transpose_w(const float* __restrict__ in, u16* __restrict__ out, int K, int N,
                 size_t ostride, size_t obase)
{
  __shared__ float t[32][33];
  const float* inp = in + (size_t)blockIdx.z * K * N;
  u16* outp = out + (size_t)blockIdx.z * ostride + obase;
  const int tx = threadIdx.x, ty = threadIdx.y;
  const int n0 = blockIdx.x << 5, k0 = blockIdx.y << 5;
  #pragma unroll
  for (int i = ty; i < 32; i += 8)
    t[i][tx] = inp[(size_t)(k0 + i) * N + n0 + tx];
  __syncthreads();
  #pragma unroll
  for (int i = ty; i < 32; i += 8)
    outp[(size_t)(n0 + i) * K + k0 + tx] = f2bf(t[tx][i]);
}

// ---------------- elementwise helpers ----------------
__global__ void addf4_k(const f32x4* __restrict__ a, const f32x4* __restrict__ b,
                        f32x4* __restrict__ o, int n)
{
  for (int i = blockIdx.x * blockDim.x + threadIdx.x; i < n; i += gridDim.x * blockDim.x)
    o[i] = a[i] + b[i];
}

__global__ void copyf4_k(const f32x4* __restrict__ a, f32x4* __restrict__ o, int n)
{
  for (int i = blockIdx.x * blockDim.x + threadIdx.x; i < n; i += gridDim.x * blockDim.x)
    o[i] = a[i];
}

__global__ void packb_k(const float* __restrict__ bq, const float* __restrict__ bk,
                        const float* __restrict__ bv, float* __restrict__ o)
{
  const int i = blockIdx.x * 256 + threadIdx.x;
  const int l = i / (3 * E_), j = i % (3 * E_);
  float v;
  if (j < E_) v = bq[l * E_ + j];
  else if (j < 2 * E_) v = bk[l * E_ + j - E_];
  else v = bv[l * E_ + j - 2 * E_];
  o[i] = v;
}

// ---------------- layernorm ----------------
template<int OUTF32>
__global__ __launch_bounds__(256)
void ln_k(const float* __restrict__ in, const float* __restrict__ gam,
          const float* __restrict__ bet, void* __restrict__ out)
{
  const int row = blockIdx.x;
  const int t = threadIdx.x;
  const f32x4 x = ((const f32x4*)(in + (size_t)row * E_))[t];
  float s = x.x + x.y + x.z + x.w;
  float s2 = x.x*x.x + x.y*x.y + x.z*x.z + x.w*x.w;
  #pragma unroll
  for (int m = 1; m < 64; m <<= 1) { s += __shfl_xor(s, m); s2 += __shfl_xor(s2, m); }
  __shared__ float red[8];
  const int w = t >> 6, lane = t & 63;
  if (lane == 0) { red[w] = s; red[4 + w] = s2; }
  __syncthreads();
  s  = red[0] + red[1] + red[2] + red[3];
  s2 = red[4] + red[5] + red[6] + red[7];
  const float mean = s * (1.0f / E_);
  const float var  = s2 * (1.0f / E_) - mean * mean;
  const float rstd = rsqrtf(var + 1e-5f);
  const f32x4 g = ((const f32x4*)gam)[t];
  const f32x4 b = ((const f32x4*)bet)[t];
  f32x4 y;
  y.x = (x.x - mean) * rstd * g.x + b.x;
  y.y = (x.y - mean) * rstd * g.y + b.y;
  y.z = (x.z - mean) * rstd * g.z + b.z;
  y.w = (x.w - mean) * rstd * g.w + b.w;
  if (OUTF32) {
    ((f32x4*)out)[(size_t)row * 256 + t] = y;
  } else {
    u16x4 p;
    p.x = f2bf(y.x); p.y = f2bf(y.y); p.z = f2bf(y.z); p.w = f2bf(y.w);
    ((u16x4*)out)[(size_t)row * 256 + t] = p;
  }
}

// ---------------- GEMM: C[M,N] = A[M,K] @ Bt[N,K]^T + bias ----------------
// Split-K via blockIdx.z: each z-slice covers K/SPLITK; MODE_RES accumulates
// with hardware fp32 atomics (exactly SPLITK contributions per address).
enum { MODE_BF16 = 0, MODE_GELU = 1, MODE_RES = 2, MODE_QKV = 4 };

template<int MODE, int SPLITK>
__global__ __launch_bounds__(256)
void gemm_k(const u16* __restrict__ A, const u16* __restrict__ Bt,
            const float* __restrict__ bias, u16* __restrict__ outb,
            float* __restrict__ outf, int N, int K)
{
  __shared__ __align__(16) u16 As[128 * 32];
  __shared__ __align__(16) u16 Bs[128 * 32];
  const int m0 = blockIdx.y << 7, n0 = blockIdx.x << 7;
  const int kbeg = (int)blockIdx.z * (K / SPLITK);
  const int kend = kbeg + K / SPLITK;
  const int tid = threadIdx.x, w = tid >> 6, lane = tid & 63;
  const int l15 = lane & 15, l4 = lane >> 4;
  const int wm = (w & 1) << 6, wn = (w >> 1) << 6;
  f32x4 acc[4][4] = {};
  const int arow0 = (w << 5) + (lane >> 2);
  const size_t aoff = (size_t)(lane & 3) << 3;
  for (int kk = kbeg; kk < kend; kk += 32) {
    const u16* ga0 = A  + (size_t)(m0 + arow0) * K + kk + aoff;
    const u16* gb0 = Bt + (size_t)(n0 + arow0) * K + kk + aoff;
    g2lds16(ga0,                  &As[((w << 5) + 0 ) * 32]);
    g2lds16(ga0 + (size_t)16 * K, &As[((w << 5) + 16) * 32]);
    g2lds16(gb0,                  &Bs[((w << 5) + 0 ) * 32]);
    g2lds16(gb0 + (size_t)16 * K, &Bs[((w << 5) + 16) * 32]);
    __syncthreads();
    bf16x8 af[4], bfr[4];
    #pragma unroll
    for (int t = 0; t < 4; ++t) {
      af[t]  = *(const bf16x8*)&As[(wm + (t << 4) + l15) * 32 + (l4 << 3)];
      bfr[t] = *(const bf16x8*)&Bs[(wn + (t << 4) + l15) * 32 + (l4 << 3)];
    }
    #pragma unroll
    for (int mt = 0; mt < 4; ++mt)
      #pragma unroll
      for (int nt = 0; nt < 4; ++nt)
        acc[mt][nt] = __builtin_amdgcn_mfma_f32_16x16x32_bf16(af[mt], bfr[nt], acc[mt][nt], 0, 0, 0);
    __syncthreads();
  }
  float bv[4];
  #pragma unroll
  for (int nt = 0; nt < 4; ++nt)
    bv[nt] = (SPLITK == 1 || blockIdx.z == 0) ? bias[n0 + wn + (nt << 4) + l15] : 0.0f;
  #pragma unroll
  for (int mt = 0; mt < 4; ++mt) {
    #pragma unroll
    for (int nt = 0; nt < 4; ++nt) {
      #pragma unroll
      for (int r = 0; r < 4; ++r) {
        const int row = m0 + wm + (mt << 4) + (l4 << 2) + r;
        const int col = n0 + wn + (nt << 4) + l15;
        float v = acc[mt][nt][r] + bv[nt];
        if (MODE == MODE_BF16) {
          outb[(size_t)row * N + col] = f2bf(v);
        } else if (MODE == MODE_GELU) {
          v = 0.5f * v * (1.0f + erff(v * 0.70710678118f));
          outb[(size_t)row * N + col] = f2bf(v);
        } else if (MODE == MODE_RES) {
          if (SPLITK == 1) outf[(size_t)row * N + col] += v;
          else unsafeAtomicAdd(&outf[(size_t)row * N + col], v);
        } else { // MODE_QKV
          const int part = col >> 10, c = col & 1023;
          if (part == 0) {
            outb[(size_t)row * E_ + c] = f2bf(v);
          } else if (part == 1) {
            outb[(size_t)R_ * E_ + (size_t)row * E_ + c] = f2bf(v);
          } else {
            const int bb = row >> 10, ss = row & 1023, hh = c >> 6, dh = c & 63;
            outb[(size_t)2 * R_ * E_ + ((size_t)((bb << 4) + hh) * DH_ + dh) * S_ + ss] = f2bf(v);
          }
        }
      }
    }
  }
}

// ---------------- flash attention, LDS-staged ----------------
__global__ __launch_bounds__(256)
void attn_k(const u16* __restrict__ q, const u16* __restrict__ kg,
            const u16* __restrict__ vT, const float* __restrict__ bias,
            u16* __restrict__ out)
{
  __shared__ __align__(16) u16 Ks[64 * 64];
  __shared__ __align__(16) u16 Vs[64 * 64];
  __shared__ __align__(16) float Bsh[64 * 64];
  __shared__ __align__(16) u16 P[4][16 * 72];
  const int tid = threadIdx.x, w = tid >> 6, lane = tid & 63;
  const int l15 = lane & 15, l4 = lane >> 4;
  const int bh = blockIdx.y, b = bh >> 4, hh = bh & 15;
  const int q0 = blockIdx.x << 6;
  const int qw = q0 + (w << 4);
  const size_t qrowbase = (size_t)(b * S_ + qw + l15) * E_ + hh * DH_ + (l4 << 3);
  const bf16x8 aq0 = *(const bf16x8*)(q + qrowbase);
  const bf16x8 aq1 = *(const bf16x8*)(q + qrowbase + 32);
  f32x4 o[4] = {};
  float mrow[4] = {-__builtin_inff(), -__builtin_inff(), -__builtin_inff(), -__builtin_inff()};
  float lrow[4] = {0.f, 0.f, 0.f, 0.f};
  u16* Pw = &P[w][0];
  const int srow = lane >> 3;
  const int scg8 = ((lane & 7) ^ srow) << 3;
  const int brow = lane >> 4;
  const int bcol = (lane & 15) << 2;
  const int kpos0 = (l4 ^ (l15 & 7)) << 3;
  const int kpos1 = ((l4 + 4) ^ (l15 & 7)) << 3;

  for (int kt = 0; kt < S_ / 64; ++kt) {
    const int kb = kt << 6;
    {
      const u16* gk = kg + (size_t)(b * S_ + kb + (w << 4) + srow) * E_ + hh * DH_ + scg8;
      g2lds16(gk,                  &Ks[(w << 10) + (lane << 3)]);
      g2lds16(gk + (size_t)8 * E_, &Ks[(w << 10) + 512 + (lane << 3)]);
      const u16* gv = vT + (size_t)(bh * DH_ + (w << 4) + srow) * S_ + kb + scg8;
      g2lds16(gv,                  &Vs[(w << 10) + (lane << 3)]);
      g2lds16(gv + (size_t)8 * S_, &Vs[(w << 10) + 512 + (lane << 3)]);
      const float* gb = bias + (size_t)(b * S_ + q0 + (w << 4) + brow) * S_ + kb + bcol;
      g2lds16(gb,                   &Bsh[(w << 10) + (lane << 2)]);
      g2lds16(gb + (size_t)4 * S_,  &Bsh[(w << 10) + 256 + (lane << 2)]);
      g2lds16(gb + (size_t)8 * S_,  &Bsh[(w << 10) + 512 + (lane << 2)]);
      g2lds16(gb + (size_t)12 * S_, &Bsh[(w << 10) + 768 + (lane << 2)]);
    }
    __syncthreads();
    f32x4 sc[4];
    #pragma unroll
    for (int nt = 0; nt < 4; ++nt) {
      const int krow = ((nt << 4) + l15) * 64;
      const bf16x8 kf0 = *(const bf16x8*)&Ks[krow + kpos0];
      const bf16x8 kf1 = *(const bf16x8*)&Ks[krow + kpos1];
      f32x4 z = {};
      z = __builtin_amdgcn_mfma_f32_16x16x32_bf16(aq0, kf0, z, 0, 0, 0);
      z = __builtin_amdgcn_mfma_f32_16x16x32_bf16(aq1, kf1, z, 0, 0, 0);
      sc[nt] = z;
    }
    float al[4];
    #pragma unroll
    for (int r = 0; r < 4; ++r) {
      const float* bp = &Bsh[((w << 4) + (l4 << 2) + r) * 64 + l15];
      float t = -__builtin_inff();
      #pragma unroll
      for (int nt = 0; nt < 4; ++nt) {
        sc[nt][r] = sc[nt][r] * 0.125f + bp[nt << 4];
        t = fmaxf(t, sc[nt][r]);
      }
      #pragma unroll
      for (int mk = 1; mk <= 8; mk <<= 1) t = fmaxf(t, __shfl_xor(t, mk));
      const float mnew = fmaxf(mrow[r], t);
      al[r] = __expf(mrow[r] - mnew);
      mrow[r] = mnew;
      float rs = 0.f;
      #pragma unroll
      for (int nt = 0; nt < 4; ++nt) {
        const float p = __expf(sc[nt][r] - mnew);
        sc[nt][r] = p;
        rs += p;
      }
      #pragma unroll
      for (int mk = 1; mk <= 8; mk <<= 1) rs += __shfl_xor(rs, mk);
      lrow[r] = lrow[r] * al[r] + rs;
    }
    #pragma unroll
    for (int ct = 0; ct < 4; ++ct) {
      o[ct][0] *= al[0]; o[ct][1] *= al[1]; o[ct][2] *= al[2]; o[ct][3] *= al[3];
    }
    #pragma unroll
    for (int nt = 0; nt < 4; ++nt)
      #pragma unroll
      for (int r = 0; r < 4; ++r)
        Pw[((l4 << 2) + r) * 72 + (nt << 4) + l15] = f2bf(sc[nt][r]);
    asm volatile("s_waitcnt lgkmcnt(0)" ::: "memory");
    const bf16x8 pa0 = *(const bf16x8*)&Pw[l15 * 72 + (l4 << 3)];
    const bf16x8 pa1 = *(const bf16x8*)&Pw[l15 * 72 + 32 + (l4 << 3)];
    #pragma unroll
    for (int ct = 0; ct < 4; ++ct) {
      const int vrow = ((ct << 4) + l15) * 64;
      const bf16x8 v0 = *(const bf16x8*)&Vs[vrow + kpos0];
      const bf16x8 v1 = *(const bf16x8*)&Vs[vrow + kpos1];
      o[ct] = __builtin_amdgcn_mfma_f32_16x16x32_bf16(pa0, v0, o[ct], 0, 0, 0);
      o[ct] = __builtin_amdgcn_mfma_f32_16x16x32_bf16(pa1, v1, o[ct], 0, 0, 0);
    }
    __syncthreads();
  }
  #pragma unroll
  for (int r = 0; r < 4; ++r) {
    const float linv = 1.0f / lrow[r];
    const size_t rowoff = (size_t)(b * S_ + qw + (l4 << 2) + r) * E_ + hh * DH_;
    #pragma unroll
    for (int ct = 0; ct < 4; ++ct)
      out[rowoff + (ct << 4) + l15] = f2bf(o[ct][r] * linv);
  }
}

// ---------------- host ----------------
extern "C" void kernel_launch(void* const* d_in, const int* in_sizes, int n_in,
                              void* d_out, int out_size, void* d_ws, size_t ws_size,
                              hipStream_t stream)
{
  (void)in_sizes; (void)n_in; (void)out_size; (void)ws_size;
  const float* src     = (const float*)d_in[0];
  const float* spatial = (const float*)d_in[1];
  const float* direc   = (const float*)d_in[2];
  const float* Wq = (const float*)d_in[3];
  const float* bq = (const float*)d_in[4];
  const float* Wk = (const float*)d_in[5];
  const float* bk = (const float*)d_in[6];
  const float* Wv = (const float*)d_in[7];
  const float* bv = (const float*)d_in[8];
  const float* Wo = (const float*)d_in[9];
  const float* bo = (const float*)d_in[10];
  const float* g1  = (const float*)d_in[11];
  const float* be1 = (const float*)d_in[12];
  const float* g2  = (const float*)d_in[13];
  const float* be2 = (const float*)d_in[14];
  const float* W1  = (const float*)d_in[15];
  const float* bf1 = (const float*)d_in[16];
  const float* W2  = (const float*)d_in[17];
  const float* bf2 = (const float*)d_in[18];
  const float* gf  = (const float*)d_in[19];
  const float* bef = (const float*)d_in[20];

  const size_t EE = (size_t)E_ * E_;
  const size_t EF = (size_t)E_ * F_;
  u16* wqkvt = (u16*)d_ws;                  // [L][3E][E]
  u16* wot = wqkvt + (size_t)L_ * 3 * EE;   // [L][E][E]
  u16* w1t = wot + (size_t)L_ * EE;         // [L][F][E]
  u16* w2t = w1t + (size_t)L_ * EF;         // [L][E][F]
  float* x = (float*)(w2t + (size_t)L_ * EF);
  u16* h   = (u16*)(x + (size_t)R_ * E_);
  u16* qb  = h  + (size_t)R_ * E_;          // q | k | vT contiguous
  u16* kb  = qb + (size_t)R_ * E_;
  u16* vtb = kb + (size_t)R_ * E_;
  u16* ab  = vtb + (size_t)R_ * E_;
  u16* mid = qb;
  float* bsum = (float*)(ab + (size_t)R_ * E_);
  float* bqkv = bsum + (size_t)B_ * S_ * S_;

  const dim3 tb(32, 8);
  transpose_w<<<dim3(E_/32, E_/32, L_), tb, 0, stream>>>(Wq, wqkvt, E_, E_, 3*EE, 0);
  transpose_w<<<dim3(E_/32, E_/32, L_), tb, 0, stream>>>(Wk, wqkvt, E_, E_, 3*EE, EE);
  transpose_w<<<dim3(E_/32, E_/32, L_), tb, 0, stream>>>(Wv, wqkvt, E_, E_, 3*EE, 2*EE);
  transpose_w<<<dim3(E_/32, E_/32, L_), tb, 0, stream>>>(Wo, wot, E_, E_, EE, 0);
  transpose_w<<<dim3(F_/32, E_/32, L_), tb, 0, stream>>>(W1, w1t, E_, F_, EF, 0);
  transpose_w<<<dim3(E_/32, F_/32, L_), tb, 0, stream>>>(W2, w2t, F_, E_, EF, 0);
  packb_k<<<(L_ * 3 * E_) / 256, 256, 0, stream>>>(bq, bk, bv, bqkv);

  const int n4 = (B_ * S_ * S_) / 4;
  addf4_k<<<1024, 256, 0, stream>>>((const f32x4*)spatial, (const f32x4*)direc, (f32x4*)bsum, n4);
  copyf4_k<<<1024, 256, 0, stream>>>((const f32x4*)src, (f32x4*)x, (R_ * E_) / 4);

  for (int l = 0; l < L_; ++l) {
    const size_t we = l * EE, wf = l * EF;
    ln_k<0><<<R_, 256, 0, stream>>>(x, g1 + l*E_, be1 + l*E_, (void*)h);
    gemm_k<MODE_QKV,1><<<dim3(3*E_/128, R_/128), 256, 0, stream>>>(h, wqkvt + l*3*EE, bqkv + (size_t)l*3*E_, qb, nullptr, 3*E_, E_);
    attn_k<<<dim3(S_/64, B_*H_), 256, 0, stream>>>(qb, kb, vtb, bsum, ab);
    gemm_k<MODE_RES,2><<<dim3(E_/128, R_/128, 2), 256, 0, stream>>>(ab, wot + we, bo + l*E_, nullptr, x, E_, E_);
    ln_k<0><<<R_, 256, 0, stream>>>(x, g2 + l*E_, be2 + l*E_, (void*)h);
    gemm_k<MODE_GELU,1><<<dim3(F_/128, R_/128), 256, 0, stream>>>(h, w1t + wf, bf1 + l*F_, mid, nullptr, F_, E_);
    gemm_k<MODE_RES,2><<<dim3(E_/128, R_/128, 2), 256, 0, stream>>>(mid, w2t + wf, bf2 + l*E_, nullptr, x, E_, F_);
  }
  ln_k<1><<<R_, 256, 0, stream>>>(x, gf, bef, d_out);
}